// Round 7
// baseline (93.329 us; speedup 1.0000x reference)
//
#include <hip/hip_runtime.h>

// YOLOv1 loss on MI355X — wave-private LDS staging (zero block barriers in
// main loop) + spread-atomic accumulation (R6's proven fix).
//
// R6 post-mortem: same-line atomic drain was the 127us plateau; fixed -> 46us.
// This round removes the remaining block-wide barrier convoy: each 64-lane
// wave owns a private 6 KB LDS region and stages its own 64-cell tile
// (per-wave DS ops execute in order; sched_barrier(0) fences pin compiler
// order — pattern proven correct in R4). 1-deep register prefetch only
// (6 float4 = 24 VGPRs; R4's spills came from the 2-deep pinned set).
//
// Inputs (setup_inputs order):
//   d_in[0] bounding_boxes: (16384,12,12,12) f32   — [x1,y1,w1,h1,c1, x2,y2,w2,h2,c2, cls0,cls1]
//   d_in[1] ground_truth:   (16384,12,12,1,12) f32 — [x,y,w,h,conf, l,u,r,d, obj, cls0,cls1]
//   d_in[2] grid_size: int scalar (8)
//   d_in[3] img_size:  int scalar (96)
// Output: 6 f32: loss, l_coord, loss_confidence, l_cls, iou_sum, object_num

#define S_DIM 12
#define CELLS_PER_IMG (S_DIM * S_DIM)      // 144
#define NCELLS (16384 * CELLS_PER_IMG)     // 2,359,296
#define GRID_BLKS 1536
#define WAVES 4
#define TPW 6                               // 1536*4*6*64 = NCELLS exact
#define NROWS 64                            // spread-atomic rows (64 B apart)
#define ROWF 16                             // floats per row (64 B)
#define L_COORD_C 5.0f
#define L_NOOBJ_C 0.5f

__device__ __forceinline__ float sq_sqrt(float t) {
    return sqrtf(fmaxf(t, 0.0f) + 1e-08f);
}

__global__ __launch_bounds__(256, 6) void yolo_loss_main(
    const float4* __restrict__ bb4,
    const float4* __restrict__ gt4,
    const int* __restrict__ gs_p,
    const int* __restrict__ im_p,
    float* __restrict__ ws)
{
    __shared__ float4 lds[WAVES][2][192];   // 24 KB, per-wave private 2x3KB
    __shared__ float red[WAVES][5];

    const int w = threadIdx.x >> 6;
    const int l = threadIdx.x & 63;
    float4* sbb = &lds[w][0][0];
    float4* sgt = &lds[w][1][0];

    const float gs = (float)(*gs_p);
    const float im = (float)(*im_p);
    const float im1 = im - 1.0f;

    float s_conf = 0.0f, s_coord = 0.0f, s_cls = 0.0f, s_iou = 0.0f, s_obj = 0.0f;

    const int tile0 = (blockIdx.x * WAVES + w) * TPW;   // 6 consecutive tiles/wave
    const float4* pb = bb4 + (size_t)tile0 * 192;
    const float4* pg = gt4 + (size_t)tile0 * 192;

    // 1-deep prefetch: tile 0 (lane-contiguous, 1 KB per wave-instruction)
    float4 r0 = pb[l], r1 = pb[64 + l], r2 = pb[128 + l];
    float4 r3 = pg[l], r4 = pg[64 + l], r5 = pg[128 + l];

    int rem = (tile0 * 64 + l) % CELLS_PER_IMG;   // lane's cell position in image

    #pragma unroll
    for (int i = 0; i < TPW; ++i) {
        // stage current tile (wave-private; per-wave DS ops are in-order)
        sbb[l] = r0; sbb[64 + l] = r1; sbb[128 + l] = r2;
        sgt[l] = r3; sgt[64 + l] = r4; sgt[128 + l] = r5;
        __builtin_amdgcn_sched_barrier(0);   // pin: writes before reads

        // issue next tile's loads; latency hides under this tile's compute
        if (i + 1 < TPW) {
            pb += 192; pg += 192;
            r0 = pb[l]; r1 = pb[64 + l]; r2 = pb[128 + l];
            r3 = pg[l]; r4 = pg[64 + l]; r5 = pg[128 + l];
        }

        // this lane's cell: stride-3 float4 LDS reads
        const float4 b0 = sbb[3 * l];       // x1,y1,w1,h1
        const float4 b1 = sbb[3 * l + 1];   // c1,x2,y2,w2
        const float4 b2 = sbb[3 * l + 2];   // h2,c2,cls0,cls1
        const float4 g0 = sgt[3 * l];       // x,y,w,h
        const float4 g1 = sgt[3 * l + 1];   // conf,l,u,r
        const float4 g2 = sgt[3 * l + 2];   // d,obj,cls0,cls1
        __builtin_amdgcn_sched_barrier(0);  // pin: reads before next iter's writes

        const float c1 = b1.x;
        const float c2 = b2.y;
        const bool sel2 = c1 < c2;

        const float p0 = sel2 ? b1.y : b0.x;
        const float p1 = sel2 ? b1.z : b0.y;
        const float p2 = sel2 ? b1.w : b0.z;
        const float p3 = sel2 ? b2.x : b0.w;
        const float p4 = sel2 ? c2   : c1;    // sel_conf
        const float other = sel2 ? c1 : c2;   // other_conf

        const bool obj = (g2.y != 0.0f);
        const float objf = obj ? 1.0f : 0.0f;

        // confidence losses
        float conf_c = L_NOOBJ_C * other * other;
        const float dconf = g1.x - p4;
        conf_c += obj ? (dconf * dconf) : (L_NOOBJ_C * p4 * p4);
        s_conf += conf_c;

        // coord loss
        const float dx = g0.x - p0;
        const float dy = g0.y - p1;
        const float dw = sq_sqrt(g0.z) - sq_sqrt(p2);
        const float dh = sq_sqrt(g0.w) - sq_sqrt(p3);
        s_coord += objf * (L_COORD_C * (dx*dx + dy*dy + dw*dw + dh*dh));

        // class loss
        const float dc0 = g2.z - b2.z;
        const float dc1 = g2.w - b2.w;
        s_cls += objf * (dc0*dc0 + dc1*dc1);

        // IoU
        const int gi = rem / S_DIM;
        const int gj = rem % S_DIM;
        const float px = truncf((float)gj * gs + p0 * gs);
        const float py = truncf((float)gi * gs + p1 * gs);
        const float pw = truncf(p2 * im);
        const float ph = truncf(p3 * im);
        const float pl = fmaxf(0.0f, px - pw * 0.5f);
        const float pu = fmaxf(0.0f, py - ph * 0.5f);
        const float pr = fminf(im1, px + pw * 0.5f);
        const float pd = fminf(im1, py + ph * 0.5f);
        const float pA = (pr - pl) * (pd - pu);
        const float gl = g1.y, gu = g1.z, gr = g1.w, gd = g2.x;
        const float gA = (gr - gl) * (gd - gu);
        const float lx = fmaxf(pl, gl);
        const float rx = fminf(pr, gr);
        const float uy = fmaxf(pu, gu);
        const float dy2 = fminf(pd, gd);
        const float inter = (rx - lx) * (dy2 - uy);
        const float iou = ((rx < lx) || (dy2 < uy)) ? 0.0f : inter / (pA + gA - inter);
        s_iou += objf * iou;

        s_obj += objf;

        rem += 64;
        if (rem >= CELLS_PER_IMG) rem -= CELLS_PER_IMG;
    }

    // wave reduction
    #pragma unroll
    for (int off = 32; off > 0; off >>= 1) {
        s_conf  += __shfl_down(s_conf,  off);
        s_coord += __shfl_down(s_coord, off);
        s_cls   += __shfl_down(s_cls,   off);
        s_iou   += __shfl_down(s_iou,   off);
        s_obj   += __shfl_down(s_obj,   off);
    }

    if (l == 0) {
        red[w][0] = s_conf;
        red[w][1] = s_coord;
        red[w][2] = s_cls;
        red[w][3] = s_iou;
        red[w][4] = s_obj;
    }
    __syncthreads();   // the only block-wide barrier, at the very end
    if (threadIdx.x == 0) {
        float t0 = 0, t1 = 0, t2 = 0, t3 = 0, t4 = 0;
        #pragma unroll
        for (int v = 0; v < WAVES; ++v) {
            t0 += red[v][0]; t1 += red[v][1]; t2 += red[v][2];
            t3 += red[v][3]; t4 += red[v][4];
        }
        // spread accumulation: row (blockIdx & 63), each row its own 64-B line
        float* row = ws + (size_t)(blockIdx.x & (NROWS - 1)) * ROWF;
        atomicAdd(&row[0], t0);  // conf
        atomicAdd(&row[1], t1);  // coord
        atomicAdd(&row[2], t2);  // cls
        atomicAdd(&row[3], t3);  // iou
        atomicAdd(&row[4], t4);  // obj count
    }
}

__global__ __launch_bounds__(64) void yolo_loss_finalize(
    const float* __restrict__ ws, float* __restrict__ out)
{
    const int l = threadIdx.x;   // 64 lanes, one row each
    const float* row = ws + (size_t)l * ROWF;
    float a0 = row[0], a1 = row[1], a2 = row[2], a3 = row[3], a4 = row[4];
    #pragma unroll
    for (int off = 32; off > 0; off >>= 1) {
        a0 += __shfl_down(a0, off);
        a1 += __shfl_down(a1, off);
        a2 += __shfl_down(a2, off);
        a3 += __shfl_down(a3, off);
        a4 += __shfl_down(a4, off);
    }
    if (l == 0) {
        out[0] = a0 + a1 + a2;  // loss = conf + coord + cls
        out[1] = a1;            // l_coord
        out[2] = a0;            // loss_confidence
        out[3] = a2;            // l_cls
        out[4] = a3;            // iou_sum
        out[5] = a4;            // object_num
    }
}

extern "C" void kernel_launch(void* const* d_in, const int* in_sizes, int n_in,
                              void* d_out, int out_size, void* d_ws, size_t ws_size,
                              hipStream_t stream) {
    const float4* bb4 = (const float4*)d_in[0];
    const float4* gt4 = (const float4*)d_in[1];
    const int* gs_p = (const int*)d_in[2];
    const int* im_p = (const int*)d_in[3];
    float* ws = (float*)d_ws;
    float* out = (float*)d_out;

    // zero the 4 KB accumulator region every launch (deterministic)
    hipMemsetAsync(d_ws, 0, NROWS * ROWF * sizeof(float), stream);

    yolo_loss_main<<<GRID_BLKS, 256, 0, stream>>>(bb4, gt4, gs_p, im_p, ws);
    yolo_loss_finalize<<<1, 64, 0, stream>>>(ws, out);
}

// Round 8
// 45.555 us; speedup vs baseline: 2.0487x; 2.0487x over previous
//
#include <hip/hip_runtime.h>

// YOLOv1 loss on MI355X — direct strided float4 loads + spread-atomic finish.
//
// Session findings so far:
//  * Same-line atomic drain (~17 ns/atomic, serialized) dominated rounds 1-5.
//    Fix (R6): spread block partials across 64 distinct 64-B lines -> 46 us.
//  * Wave-private free-running staging (R7) REGRESSED (93 us, FETCH +56%):
//    block-synchronized access keeps the device's concurrent read window
//    compact and cache-friendly. Lockstep is good here.
//  * R1's direct 48B-stride float4 loads showed clean FETCH (113 MB) — its
//    slowness was entirely the atomic drain. So: drop LDS staging entirely
//    (save 12 DS ops + 2 barriers + 1.66M conflict cycles per tile) and pair
//    direct loads with the spread-atomic finish.
//
// Inputs (setup_inputs order):
//   d_in[0] bounding_boxes: (16384,12,12,12) f32   — [x1,y1,w1,h1,c1, x2,y2,w2,h2,c2, cls0,cls1]
//   d_in[1] ground_truth:   (16384,12,12,1,12) f32 — [x,y,w,h,conf, l,u,r,d, obj, cls0,cls1]
//   d_in[2] grid_size: int scalar (8)
//   d_in[3] img_size:  int scalar (96)
// Output: 6 f32: loss, l_coord, loss_confidence, l_cls, iou_sum, object_num

#define S_DIM 12
#define CELLS_PER_IMG (S_DIM * S_DIM)      // 144
#define NCELLS (16384 * CELLS_PER_IMG)     // 2,359,296 = 256 * 9216
#define GRID_BLKS 2304                      // 9 blocks/CU
#define ITERS 4                             // 2304 * 256 * 4 = NCELLS exact
#define CELL_STRIDE (GRID_BLKS * 256)       // 589,824 cells between iterations
#define NROWS 64                            // spread-atomic rows (64 B apart)
#define ROWF 16                             // floats per row (64 B)
#define L_COORD_C 5.0f
#define L_NOOBJ_C 0.5f

__device__ __forceinline__ float sq_sqrt(float t) {
    return sqrtf(fmaxf(t, 0.0f) + 1e-08f);
}

__global__ __launch_bounds__(256) void yolo_loss_main(
    const float4* __restrict__ bb4,
    const float4* __restrict__ gt4,
    const int* __restrict__ gs_p,
    const int* __restrict__ im_p,
    float* __restrict__ ws)
{
    const float gs = (float)(*gs_p);
    const float im = (float)(*im_p);
    const float im1 = im - 1.0f;

    float s_conf = 0.0f, s_coord = 0.0f, s_cls = 0.0f, s_iou = 0.0f, s_obj = 0.0f;

    const int base = blockIdx.x * 256 + threadIdx.x;

    #pragma unroll
    for (int it = 0; it < ITERS; ++it) {
        const int n = base + it * CELL_STRIDE;   // lane-adjacent cells each iter
        const float4* pb = bb4 + (size_t)n * 3;  // 48 B per cell per input
        const float4* pg = gt4 + (size_t)n * 3;

        const float4 b0 = pb[0];   // x1,y1,w1,h1
        const float4 b1 = pb[1];   // c1,x2,y2,w2
        const float4 b2 = pb[2];   // h2,c2,cls0,cls1
        const float4 g0 = pg[0];   // x,y,w,h
        const float4 g1 = pg[1];   // conf,l,u,r
        const float4 g2 = pg[2];   // d,obj,cls0,cls1

        const float c1 = b1.x;
        const float c2 = b2.y;
        const bool sel2 = c1 < c2;

        const float p0 = sel2 ? b1.y : b0.x;
        const float p1 = sel2 ? b1.z : b0.y;
        const float p2 = sel2 ? b1.w : b0.z;
        const float p3 = sel2 ? b2.x : b0.w;
        const float p4 = sel2 ? c2   : c1;    // sel_conf
        const float other = sel2 ? c1 : c2;   // other_conf

        const bool obj = (g2.y != 0.0f);
        const float objf = obj ? 1.0f : 0.0f;

        // confidence losses
        float conf_c = L_NOOBJ_C * other * other;
        const float dconf = g1.x - p4;
        conf_c += obj ? (dconf * dconf) : (L_NOOBJ_C * p4 * p4);
        s_conf += conf_c;

        // coord loss
        const float dx = g0.x - p0;
        const float dy = g0.y - p1;
        const float dw = sq_sqrt(g0.z) - sq_sqrt(p2);
        const float dh = sq_sqrt(g0.w) - sq_sqrt(p3);
        s_coord += objf * (L_COORD_C * (dx*dx + dy*dy + dw*dw + dh*dh));

        // class loss
        const float dc0 = g2.z - b2.z;
        const float dc1 = g2.w - b2.w;
        s_cls += objf * (dc0*dc0 + dc1*dc1);

        // IoU
        const int rem = n % CELLS_PER_IMG;
        const int gi = rem / S_DIM;
        const int gj = rem % S_DIM;
        const float px = truncf((float)gj * gs + p0 * gs);
        const float py = truncf((float)gi * gs + p1 * gs);
        const float pw = truncf(p2 * im);
        const float ph = truncf(p3 * im);
        const float pl = fmaxf(0.0f, px - pw * 0.5f);
        const float pu = fmaxf(0.0f, py - ph * 0.5f);
        const float pr = fminf(im1, px + pw * 0.5f);
        const float pd = fminf(im1, py + ph * 0.5f);
        const float pA = (pr - pl) * (pd - pu);
        const float gl = g1.y, gu = g1.z, gr = g1.w, gd = g2.x;
        const float gA = (gr - gl) * (gd - gu);
        const float lx = fmaxf(pl, gl);
        const float rx = fminf(pr, gr);
        const float uy = fmaxf(pu, gu);
        const float dy2 = fminf(pd, gd);
        const float inter = (rx - lx) * (dy2 - uy);
        const float iou = ((rx < lx) || (dy2 < uy)) ? 0.0f : inter / (pA + gA - inter);
        s_iou += objf * iou;

        s_obj += objf;
    }

    // wave reduction
    #pragma unroll
    for (int off = 32; off > 0; off >>= 1) {
        s_conf  += __shfl_down(s_conf,  off);
        s_coord += __shfl_down(s_coord, off);
        s_cls   += __shfl_down(s_cls,   off);
        s_iou   += __shfl_down(s_iou,   off);
        s_obj   += __shfl_down(s_obj,   off);
    }

    __shared__ float red[4][5];
    const int w = threadIdx.x >> 6;
    const int l = threadIdx.x & 63;
    if (l == 0) {
        red[w][0] = s_conf;
        red[w][1] = s_coord;
        red[w][2] = s_cls;
        red[w][3] = s_iou;
        red[w][4] = s_obj;
    }
    __syncthreads();
    if (threadIdx.x == 0) {
        float t0 = 0, t1 = 0, t2 = 0, t3 = 0, t4 = 0;
        #pragma unroll
        for (int v = 0; v < 4; ++v) {
            t0 += red[v][0]; t1 += red[v][1]; t2 += red[v][2];
            t3 += red[v][3]; t4 += red[v][4];
        }
        // spread accumulation: row (blockIdx & 63), each row its own 64-B line
        float* row = ws + (size_t)(blockIdx.x & (NROWS - 1)) * ROWF;
        atomicAdd(&row[0], t0);  // conf (no_other + no_sel + conf_obj)
        atomicAdd(&row[1], t1);  // coord
        atomicAdd(&row[2], t2);  // cls
        atomicAdd(&row[3], t3);  // iou
        atomicAdd(&row[4], t4);  // obj count
    }
}

__global__ __launch_bounds__(64) void yolo_loss_finalize(
    const float* __restrict__ ws, float* __restrict__ out)
{
    const int l = threadIdx.x;   // 64 lanes, one row each
    const float* row = ws + (size_t)l * ROWF;
    float a0 = row[0], a1 = row[1], a2 = row[2], a3 = row[3], a4 = row[4];
    #pragma unroll
    for (int off = 32; off > 0; off >>= 1) {
        a0 += __shfl_down(a0, off);
        a1 += __shfl_down(a1, off);
        a2 += __shfl_down(a2, off);
        a3 += __shfl_down(a3, off);
        a4 += __shfl_down(a4, off);
    }
    if (l == 0) {
        out[0] = a0 + a1 + a2;  // loss = conf + coord + cls
        out[1] = a1;            // l_coord
        out[2] = a0;            // loss_confidence
        out[3] = a2;            // l_cls
        out[4] = a3;            // iou_sum
        out[5] = a4;            // object_num
    }
}

extern "C" void kernel_launch(void* const* d_in, const int* in_sizes, int n_in,
                              void* d_out, int out_size, void* d_ws, size_t ws_size,
                              hipStream_t stream) {
    const float4* bb4 = (const float4*)d_in[0];
    const float4* gt4 = (const float4*)d_in[1];
    const int* gs_p = (const int*)d_in[2];
    const int* im_p = (const int*)d_in[3];
    float* ws = (float*)d_ws;
    float* out = (float*)d_out;

    // zero the 4 KB accumulator region every launch (deterministic)
    hipMemsetAsync(d_ws, 0, NROWS * ROWF * sizeof(float), stream);

    yolo_loss_main<<<GRID_BLKS, 256, 0, stream>>>(bb4, gt4, gs_p, im_p, ws);
    yolo_loss_finalize<<<1, 64, 0, stream>>>(ws, out);
}